// Round 1
// baseline (421.324 us; speedup 1.0000x reference)
//
#include <hip/hip_runtime.h>
#include <hip/hip_bf16.h>
#include <cstdint>
#include <cstddef>

#define B_DIM 4096
#define IN_F 4096
#define OUT_F 4096
#define NNZ_N 1677722

typedef short short8 __attribute__((ext_vector_type(8)));
typedef float floatx4 __attribute__((ext_vector_type(4)));
typedef unsigned short ushort8 __attribute__((ext_vector_type(8)));

// ---------------------------------------------------------------------------
// Kernel 1: scatter COO values into dense W [OUT_F][IN_F] f32 (duplicates add)
// ---------------------------------------------------------------------------
__global__ __launch_bounds__(256) void scatter_coo(
    const float* __restrict__ vals, const int* __restrict__ rows,
    const int* __restrict__ cols, float* __restrict__ W) {
  int i = blockIdx.x * blockDim.x + threadIdx.x;
  if (i < NNZ_N) {
    atomicAdd(W + (size_t)rows[i] * IN_F + (size_t)cols[i], vals[i]);
  }
}

// ---------------------------------------------------------------------------
// Kernel 2: f32 -> bf16 (RNE), 8 elements/thread, 16B stores
// ---------------------------------------------------------------------------
__device__ inline unsigned short f2bf(float f) {
  union { float f; unsigned int u; } v;
  v.f = f;
  unsigned int u = v.u;
  return (unsigned short)((u + 0x7fffu + ((u >> 16) & 1u)) >> 16);
}

__global__ __launch_bounds__(256) void cvt_f32_bf16x8(
    const float* __restrict__ src, unsigned short* __restrict__ dst) {
  size_t i = ((size_t)blockIdx.x * blockDim.x + threadIdx.x) * 8;
  float4 a = *(const float4*)(src + i);
  float4 b = *(const float4*)(src + i + 4);
  ushort8 o;
  o[0] = f2bf(a.x); o[1] = f2bf(a.y); o[2] = f2bf(a.z); o[3] = f2bf(a.w);
  o[4] = f2bf(b.x); o[5] = f2bf(b.y); o[6] = f2bf(b.z); o[7] = f2bf(b.w);
  *(ushort8*)(dst + i) = o;
}

// ---------------------------------------------------------------------------
// Kernel 3: bf16 MFMA GEMM, C = A * B^T + bias
//   A  = xb [B_DIM][IN_F] bf16 (row-major, K contiguous)
//   Bt = wb [OUT_F][IN_F] bf16 (row-major, K contiguous)  -> C[m][n]
// 128x128 tile, BK=64, 4 waves (2x2), 16x16x32 MFMA, global_load_lds staging.
// ---------------------------------------------------------------------------
__device__ inline void load_lds16(const unsigned short* g,
                                  const unsigned short* lds_base) {
  __builtin_amdgcn_global_load_lds(
      (const __attribute__((address_space(1))) unsigned int*)g,
      (__attribute__((address_space(3))) unsigned int*)lds_base, 16, 0, 0);
}

__global__ __launch_bounds__(256) void gemm_bt_bf16(
    const unsigned short* __restrict__ A, const unsigned short* __restrict__ Bt,
    const float* __restrict__ bias, float* __restrict__ C) {
  __shared__ unsigned short lA[128 * 64];  // [row][k], unpadded (global_load_lds)
  __shared__ unsigned short lB[128 * 64];

  const int tid = threadIdx.x;
  const int wid = tid >> 6;
  const int lane = tid & 63;

  const int bm0 = blockIdx.y * 128;
  const int bn0 = blockIdx.x * 128;

  const int wm = (wid >> 1) * 64;  // wave's m offset inside tile
  const int wn = (wid & 1) * 64;   // wave's n offset inside tile

  floatx4 acc[4][4];
#pragma unroll
  for (int i = 0; i < 4; ++i)
#pragma unroll
    for (int j = 0; j < 4; ++j) acc[i][j] = (floatx4)0.0f;

  // staging: each wave fills rows [wid*32, wid*32+32) of each tile,
  // 4 insts x (64 lanes x 16B = 1KB = 8 rows of 128B)
  const int ldr = lane >> 3;             // row within 8-row group
  const int ldc = (lane & 7) * 8;        // k element offset (16B chunks)

  const unsigned short* gA = A + (size_t)(bm0 + wid * 32) * IN_F;
  const unsigned short* gB = Bt + (size_t)(bn0 + wid * 32) * IN_F;

  for (int k0 = 0; k0 < IN_F; k0 += 64) {
#pragma unroll
    for (int j = 0; j < 4; ++j) {
      load_lds16(gA + (size_t)(j * 8 + ldr) * IN_F + k0 + ldc,
                 &lA[(wid * 32 + j * 8) * 64]);
      load_lds16(gB + (size_t)(j * 8 + ldr) * IN_F + k0 + ldc,
                 &lB[(wid * 32 + j * 8) * 64]);
    }
    __syncthreads();  // compiler emits vmcnt(0) drain before s_barrier

    const int rr = lane & 15;
#pragma unroll
    for (int ks = 0; ks < 2; ++ks) {
      const int kc = ks * 32 + (lane >> 4) * 8;
      short8 af[4], bf[4];
#pragma unroll
      for (int i = 0; i < 4; ++i)
        af[i] = *(const short8*)&lA[(wm + i * 16 + rr) * 64 + kc];
#pragma unroll
      for (int j = 0; j < 4; ++j)
        bf[j] = *(const short8*)&lB[(wn + j * 16 + rr) * 64 + kc];
#pragma unroll
      for (int i = 0; i < 4; ++i)
#pragma unroll
        for (int j = 0; j < 4; ++j)
          acc[i][j] = __builtin_amdgcn_mfma_f32_16x16x32_bf16(
              af[i], bf[j], acc[i][j], 0, 0, 0);
    }
    __syncthreads();
  }

  // epilogue: C/D layout col=lane&15, row=(lane>>4)*4+reg
  const int cn = lane & 15;
  const int r0 = (lane >> 4) * 4;
#pragma unroll
  for (int j = 0; j < 4; ++j) {
    const int col = bn0 + wn + j * 16 + cn;
    const float bv = bias[col];
#pragma unroll
    for (int i = 0; i < 4; ++i) {
#pragma unroll
      for (int r = 0; r < 4; ++r) {
        const int row = bm0 + wm + i * 16 + r0 + r;
        C[(size_t)row * OUT_F + col] = acc[i][j][r] + bv;
      }
    }
  }
}

// ---------------------------------------------------------------------------
extern "C" void kernel_launch(void* const* d_in, const int* in_sizes, int n_in,
                              void* d_out, int out_size, void* d_ws,
                              size_t ws_size, hipStream_t stream) {
  const float* x = (const float*)d_in[0];
  const float* vals = (const float*)d_in[1];
  const int* rows = (const int*)d_in[2];
  const int* cols = (const int*)d_in[3];
  const float* bias = (const float*)d_in[4];
  float* out = (float*)d_out;

  // workspace layout: W f32 (64MB) | wb bf16 (32MB) | xb bf16 (32MB)
  float* W = (float*)d_ws;
  unsigned short* wb = (unsigned short*)((char*)d_ws + ((size_t)64 << 20));
  unsigned short* xb = (unsigned short*)((char*)d_ws + ((size_t)96 << 20));

  hipMemsetAsync(W, 0, (size_t)OUT_F * IN_F * sizeof(float), stream);
  scatter_coo<<<(NNZ_N + 255) / 256, 256, 0, stream>>>(vals, rows, cols, W);
  cvt_f32_bf16x8<<<(size_t)OUT_F * IN_F / 8 / 256, 256, 0, stream>>>(W, wb);
  cvt_f32_bf16x8<<<(size_t)B_DIM * IN_F / 8 / 256, 256, 0, stream>>>(x, xb);

  dim3 grid(OUT_F / 128, B_DIM / 128);
  gemm_bt_bf16<<<grid, 256, 0, stream>>>(xb, wb, bias, out);
}

// Round 2
// 385.244 us; speedup vs baseline: 1.0937x; 1.0937x over previous
//
#include <hip/hip_runtime.h>
#include <hip/hip_bf16.h>
#include <cstdint>
#include <cstddef>

#define B_DIM 4096
#define IN_F 4096
#define OUT_F 4096
#define NNZ_N 1677722

typedef short short8 __attribute__((ext_vector_type(8)));
typedef float floatx4 __attribute__((ext_vector_type(4)));
typedef unsigned short ushort8 __attribute__((ext_vector_type(8)));

// ---------------------------------------------------------------------------
// Kernel 1: scatter COO values into dense W [OUT_F][IN_F] f32 (duplicates add)
// ---------------------------------------------------------------------------
__global__ __launch_bounds__(256) void scatter_coo(
    const float* __restrict__ vals, const int* __restrict__ rows,
    const int* __restrict__ cols, float* __restrict__ W) {
  int i = blockIdx.x * blockDim.x + threadIdx.x;
  if (i < NNZ_N) {
    atomicAdd(W + (size_t)rows[i] * IN_F + (size_t)cols[i], vals[i]);
  }
}

// ---------------------------------------------------------------------------
// Kernel 2: f32 -> bf16 (RNE), 8 elements/thread, 16B stores
// ---------------------------------------------------------------------------
__device__ inline unsigned short f2bf(float f) {
  union { float f; unsigned int u; } v;
  v.f = f;
  unsigned int u = v.u;
  return (unsigned short)((u + 0x7fffu + ((u >> 16) & 1u)) >> 16);
}

__global__ __launch_bounds__(256) void cvt_f32_bf16x8(
    const float* __restrict__ src, unsigned short* __restrict__ dst) {
  size_t i = ((size_t)blockIdx.x * blockDim.x + threadIdx.x) * 8;
  float4 a = *(const float4*)(src + i);
  float4 b = *(const float4*)(src + i + 4);
  ushort8 o;
  o[0] = f2bf(a.x); o[1] = f2bf(a.y); o[2] = f2bf(a.z); o[3] = f2bf(a.w);
  o[4] = f2bf(b.x); o[5] = f2bf(b.y); o[6] = f2bf(b.z); o[7] = f2bf(b.w);
  *(ushort8*)(dst + i) = o;
}

// ---------------------------------------------------------------------------
// Kernel 3: bf16 MFMA GEMM, C = A * B^T + bias
//   A  = xb [B_DIM][IN_F] bf16 (row-major, K contiguous)
//   Bt = wb [OUT_F][IN_F] bf16 (row-major, K contiguous)  -> C[m][n]
// 128x128 tile, BK=64, 4 waves (2x2), 16x16x32 MFMA, global_load_lds staging.
//
// LDS layout is XOR-swizzled to kill ds_read_b128 bank conflicts:
//   LDS[row][chunk] = global[row][chunk ^ (row & 7)]   (chunk = 8 bf16 = 16B)
// global_load_lds forces dest = base + lane*16, so the swizzle is applied to
// the GLOBAL chunk each staging lane fetches; fragment reads XOR the chunk
// index with (row & 7). Row stride stays 128B (bank-aligned), but the 16
// lanes of each quarter-group now cover all 8 chunk positions -> 32 banks at
// 2-way aliasing (free, m136) instead of a 16-way pileup on 4 banks.
// ---------------------------------------------------------------------------
__device__ inline void load_lds16(const unsigned short* g,
                                  const unsigned short* lds_base) {
  __builtin_amdgcn_global_load_lds(
      (const __attribute__((address_space(1))) unsigned int*)g,
      (__attribute__((address_space(3))) unsigned int*)lds_base, 16, 0, 0);
}

__global__ __launch_bounds__(256) void gemm_bt_bf16(
    const unsigned short* __restrict__ A, const unsigned short* __restrict__ Bt,
    const float* __restrict__ bias, float* __restrict__ C) {
  __shared__ unsigned short lA[128 * 64];  // [row][k] XOR-swizzled, unpadded
  __shared__ unsigned short lB[128 * 64];

  const int tid = threadIdx.x;
  const int wid = tid >> 6;
  const int lane = tid & 63;

  const int bm0 = blockIdx.y * 128;
  const int bn0 = blockIdx.x * 128;

  const int wm = (wid >> 1) * 64;  // wave's m offset inside tile
  const int wn = (wid & 1) * 64;   // wave's n offset inside tile

  floatx4 acc[4][4];
#pragma unroll
  for (int i = 0; i < 4; ++i)
#pragma unroll
    for (int j = 0; j < 4; ++j) acc[i][j] = (floatx4)0.0f;

  // staging: each wave fills rows [wid*32, wid*32+32) of each tile,
  // 4 insts x (64 lanes x 16B = 1KB = 8 rows of 128B).
  // lane l lands at LDS row (l>>3), chunk (l&7); fetch global chunk
  // (l&7) ^ ((l>>3)&7) so LDS holds the XOR-swizzled layout.
  const int ldr = lane >> 3;                         // row within 8-row group
  const int ldc = ((lane & 7) ^ (ldr & 7)) * 8;      // swizzled k element off

  const unsigned short* gA = A + (size_t)(bm0 + wid * 32) * IN_F;
  const unsigned short* gB = Bt + (size_t)(bn0 + wid * 32) * IN_F;

  for (int k0 = 0; k0 < IN_F; k0 += 64) {
#pragma unroll
    for (int j = 0; j < 4; ++j) {
      load_lds16(gA + (size_t)(j * 8 + ldr) * IN_F + k0 + ldc,
                 &lA[(wid * 32 + j * 8) * 64]);
      load_lds16(gB + (size_t)(j * 8 + ldr) * IN_F + k0 + ldc,
                 &lB[(wid * 32 + j * 8) * 64]);
    }
    __syncthreads();

    const int rr = lane & 15;       // fragment row within 16
    const int rx = rr & 7;          // swizzle key (tile row ≡ rr mod 8)
    const int kq = lane >> 4;       // k quarter 0..3
#pragma unroll
    for (int ks = 0; ks < 2; ++ks) {
      const int kchunk = ks * 4 + kq;          // 16B chunk index 0..7
      const int kcs = ((kchunk ^ rx) << 3);    // swizzled element offset
      short8 af[4], bf[4];
#pragma unroll
      for (int i = 0; i < 4; ++i)
        af[i] = *(const short8*)&lA[(wm + i * 16 + rr) * 64 + kcs];
#pragma unroll
      for (int j = 0; j < 4; ++j)
        bf[j] = *(const short8*)&lB[(wn + j * 16 + rr) * 64 + kcs];
#pragma unroll
      for (int i = 0; i < 4; ++i)
#pragma unroll
        for (int j = 0; j < 4; ++j)
          acc[i][j] = __builtin_amdgcn_mfma_f32_16x16x32_bf16(
              af[i], bf[j], acc[i][j], 0, 0, 0);
    }
    __syncthreads();
  }

  // epilogue: C/D layout col=lane&15, row=(lane>>4)*4+reg
  const int cn = lane & 15;
  const int r0 = (lane >> 4) * 4;
#pragma unroll
  for (int j = 0; j < 4; ++j) {
    const int col = bn0 + wn + j * 16 + cn;
    const float bv = bias[col];
#pragma unroll
    for (int i = 0; i < 4; ++i) {
#pragma unroll
      for (int r = 0; r < 4; ++r) {
        const int row = bm0 + wm + i * 16 + r0 + r;
        C[(size_t)row * OUT_F + col] = acc[i][j][r] + bv;
      }
    }
  }
}

// ---------------------------------------------------------------------------
extern "C" void kernel_launch(void* const* d_in, const int* in_sizes, int n_in,
                              void* d_out, int out_size, void* d_ws,
                              size_t ws_size, hipStream_t stream) {
  const float* x = (const float*)d_in[0];
  const float* vals = (const float*)d_in[1];
  const int* rows = (const int*)d_in[2];
  const int* cols = (const int*)d_in[3];
  const float* bias = (const float*)d_in[4];
  float* out = (float*)d_out;

  // workspace layout: W f32 (64MB) | wb bf16 (32MB) | xb bf16 (32MB)
  float* W = (float*)d_ws;
  unsigned short* wb = (unsigned short*)((char*)d_ws + ((size_t)64 << 20));
  unsigned short* xb = (unsigned short*)((char*)d_ws + ((size_t)96 << 20));

  hipMemsetAsync(W, 0, (size_t)OUT_F * IN_F * sizeof(float), stream);
  scatter_coo<<<(NNZ_N + 255) / 256, 256, 0, stream>>>(vals, rows, cols, W);
  cvt_f32_bf16x8<<<(size_t)OUT_F * IN_F / 8 / 256, 256, 0, stream>>>(W, wb);
  cvt_f32_bf16x8<<<(size_t)B_DIM * IN_F / 8 / 256, 256, 0, stream>>>(x, xb);

  dim3 grid(OUT_F / 128, B_DIM / 128);
  gemm_bt_bf16<<<grid, 256, 0, stream>>>(xb, wb, bias, out);
}

// Round 4
// 358.010 us; speedup vs baseline: 1.1769x; 1.0761x over previous
//
#include <hip/hip_runtime.h>
#include <hip/hip_bf16.h>
#include <cstdint>
#include <cstddef>

#define B_DIM 4096
#define IN_F 4096
#define OUT_F 4096
#define NNZ_N 1677722

typedef short short8 __attribute__((ext_vector_type(8)));
typedef float floatx4 __attribute__((ext_vector_type(4)));
typedef unsigned short ushort8 __attribute__((ext_vector_type(8)));

// ---------------------------------------------------------------------------
// f32 -> bf16 RNE
// ---------------------------------------------------------------------------
__device__ inline unsigned short f2bf(float f) {
  union { float f; unsigned int u; } v;
  v.f = f;
  unsigned int u = v.u;
  return (unsigned short)((u + 0x7fffu + ((u >> 16) & 1u)) >> 16);
}

// packed bf16x2 atomic add — raw gfx950 instruction via inline asm.
// (ROCm 7.2 exposes neither a bf16x2 atomicAdd overload nor the
// __builtin_amdgcn_global_atomic_fadd_v2bf16 builtin on the host pass;
// inline asm guarded by __HIP_DEVICE_COMPILE__ sidesteps both.)
__device__ inline void pk_atomic_add_bf16(unsigned int* p, unsigned int packed) {
#if defined(__HIP_DEVICE_COMPILE__)
  asm volatile("global_atomic_pk_add_bf16 %0, %1, off"
               :
               : "v"(p), "v"(packed)
               : "memory");
#endif
}

// ---------------------------------------------------------------------------
// Fused: COO scatter (bf16 pk-atomic into wb) + x f32->bf16 convert.
// Scatter blocks first (long pole), cvt blocks after; streaming cvt traffic
// overlaps the random-atomic latency on the memory system.
// ---------------------------------------------------------------------------
#define SCAT_BLOCKS ((NNZ_N + 255) / 256)          // 6554
#define CVT_BLOCKS ((B_DIM * IN_F) / 8 / 256)      // 8192

__global__ __launch_bounds__(256) void fused_scatter_cvt(
    const float* __restrict__ vals, const int* __restrict__ rows,
    const int* __restrict__ cols, unsigned int* __restrict__ Wb2,
    const float* __restrict__ x, unsigned short* __restrict__ xb) {
  const int b = blockIdx.x;
  if (b < SCAT_BLOCKS) {
    int i = b * 256 + threadIdx.x;
    if (i < NNZ_N) {
      int r = rows[i];
      int c = cols[i];
      unsigned int bv = f2bf(vals[i]);
      unsigned int packed = (c & 1) ? (bv << 16) : bv;
      pk_atomic_add_bf16(Wb2 + ((((size_t)r << 12) | (size_t)c) >> 1), packed);
    }
  } else {
    size_t i = ((size_t)(b - SCAT_BLOCKS) * 256 + threadIdx.x) * 8;
    float4 a = *(const float4*)(x + i);
    float4 f = *(const float4*)(x + i + 4);
    ushort8 o;
    o[0] = f2bf(a.x); o[1] = f2bf(a.y); o[2] = f2bf(a.z); o[3] = f2bf(a.w);
    o[4] = f2bf(f.x); o[5] = f2bf(f.y); o[6] = f2bf(f.z); o[7] = f2bf(f.w);
    *(ushort8*)(xb + i) = o;
  }
}

// ---------------------------------------------------------------------------
// bf16 MFMA GEMM, C = A * B^T + bias
//   A  = xb [B_DIM][IN_F] bf16 (row-major, K contiguous)
//   Bt = wb [OUT_F][IN_F] bf16 (row-major, K contiguous)  -> C[m][n]
// 128x128 tile, BK=64, 4 waves (2x2), 16x16x32 MFMA, global_load_lds staging.
//
// LDS layout is XOR-swizzled to kill ds_read_b128 bank conflicts:
//   LDS[row][chunk] = global[row][chunk ^ (row & 7)]   (chunk = 8 bf16 = 16B)
// (measured R1->R2: SQ_LDS_BANK_CONFLICT 5.03e7 -> 0, GEMM 206 -> 170 us)
// ---------------------------------------------------------------------------
__device__ inline void load_lds16(const unsigned short* g,
                                  const unsigned short* lds_base) {
  __builtin_amdgcn_global_load_lds(
      (const __attribute__((address_space(1))) unsigned int*)g,
      (__attribute__((address_space(3))) unsigned int*)lds_base, 16, 0, 0);
}

__global__ __launch_bounds__(256) void gemm_bt_bf16(
    const unsigned short* __restrict__ A, const unsigned short* __restrict__ Bt,
    const float* __restrict__ bias, float* __restrict__ C) {
  __shared__ unsigned short lA[128 * 64];  // [row][k] XOR-swizzled, unpadded
  __shared__ unsigned short lB[128 * 64];

  const int tid = threadIdx.x;
  const int wid = tid >> 6;
  const int lane = tid & 63;

  const int bm0 = blockIdx.y * 128;
  const int bn0 = blockIdx.x * 128;

  const int wm = (wid >> 1) * 64;  // wave's m offset inside tile
  const int wn = (wid & 1) * 64;   // wave's n offset inside tile

  floatx4 acc[4][4];
#pragma unroll
  for (int i = 0; i < 4; ++i)
#pragma unroll
    for (int j = 0; j < 4; ++j) acc[i][j] = (floatx4)0.0f;

  const int ldr = lane >> 3;                     // row within 8-row group
  const int ldc = ((lane & 7) ^ (ldr & 7)) * 8;  // swizzled k element offset

  const unsigned short* gA = A + (size_t)(bm0 + wid * 32) * IN_F;
  const unsigned short* gB = Bt + (size_t)(bn0 + wid * 32) * IN_F;

  for (int k0 = 0; k0 < IN_F; k0 += 64) {
#pragma unroll
    for (int j = 0; j < 4; ++j) {
      load_lds16(gA + (size_t)(j * 8 + ldr) * IN_F + k0 + ldc,
                 &lA[(wid * 32 + j * 8) * 64]);
      load_lds16(gB + (size_t)(j * 8 + ldr) * IN_F + k0 + ldc,
                 &lB[(wid * 32 + j * 8) * 64]);
    }
    __syncthreads();

    const int rr = lane & 15;       // fragment row within 16
    const int rx = rr & 7;          // swizzle key
    const int kq = lane >> 4;       // k quarter 0..3
#pragma unroll
    for (int ks = 0; ks < 2; ++ks) {
      const int kchunk = ks * 4 + kq;
      const int kcs = ((kchunk ^ rx) << 3);
      short8 af[4], bf[4];
#pragma unroll
      for (int i = 0; i < 4; ++i)
        af[i] = *(const short8*)&lA[(wm + i * 16 + rr) * 64 + kcs];
#pragma unroll
      for (int j = 0; j < 4; ++j)
        bf[j] = *(const short8*)&lB[(wn + j * 16 + rr) * 64 + kcs];
#pragma unroll
      for (int i = 0; i < 4; ++i)
#pragma unroll
        for (int j = 0; j < 4; ++j)
          acc[i][j] = __builtin_amdgcn_mfma_f32_16x16x32_bf16(
              af[i], bf[j], acc[i][j], 0, 0, 0);
    }
    __syncthreads();
  }

  // epilogue: C/D layout col=lane&15, row=(lane>>4)*4+reg
  const int cn = lane & 15;
  const int r0 = (lane >> 4) * 4;
#pragma unroll
  for (int j = 0; j < 4; ++j) {
    const int col = bn0 + wn + j * 16 + cn;
    const float bv = bias[col];
#pragma unroll
    for (int i = 0; i < 4; ++i) {
#pragma unroll
      for (int r = 0; r < 4; ++r) {
        const int row = bm0 + wm + i * 16 + r0 + r;
        C[(size_t)row * OUT_F + col] = acc[i][j][r] + bv;
      }
    }
  }
}

// ---------------------------------------------------------------------------
extern "C" void kernel_launch(void* const* d_in, const int* in_sizes, int n_in,
                              void* d_out, int out_size, void* d_ws,
                              size_t ws_size, hipStream_t stream) {
  const float* x = (const float*)d_in[0];
  const float* vals = (const float*)d_in[1];
  const int* rows = (const int*)d_in[2];
  const int* cols = (const int*)d_in[3];
  const float* bias = (const float*)d_in[4];
  float* out = (float*)d_out;

  // workspace layout: wb bf16 (32MB) | xb bf16 (32MB)
  unsigned short* wb = (unsigned short*)d_ws;
  unsigned short* xb = (unsigned short*)((char*)d_ws + ((size_t)32 << 20));

  (void)hipMemsetAsync(wb, 0, (size_t)OUT_F * IN_F * sizeof(unsigned short),
                       stream);
  fused_scatter_cvt<<<SCAT_BLOCKS + CVT_BLOCKS, 256, 0, stream>>>(
      vals, rows, cols, (unsigned int*)wb, x, xb);

  dim3 grid(OUT_F / 128, B_DIM / 128);
  gemm_bt_bf16<<<grid, 256, 0, stream>>>(xb, wb, bias, out);
}

// Round 5
// 345.893 us; speedup vs baseline: 1.2181x; 1.0350x over previous
//
#include <hip/hip_runtime.h>
#include <hip/hip_bf16.h>
#include <cstdint>
#include <cstddef>

#define B_DIM 4096
#define IN_F 4096
#define OUT_F 4096
#define NNZ_N 1677722

typedef short short8 __attribute__((ext_vector_type(8)));
typedef float floatx4 __attribute__((ext_vector_type(4)));
typedef unsigned short ushort8 __attribute__((ext_vector_type(8)));

// ---------------------------------------------------------------------------
// f32 -> bf16 RNE
// ---------------------------------------------------------------------------
__device__ inline unsigned short f2bf(float f) {
  union { float f; unsigned int u; } v;
  v.f = f;
  unsigned int u = v.u;
  return (unsigned short)((u + 0x7fffu + ((u >> 16) & 1u)) >> 16);
}

// ---------------------------------------------------------------------------
// Bucketed densification (replaces 1.67M device-scope atomics, which measured
// ~11 G atomics/s = ~150 us regardless of footprint in R1..R4):
//   P1: partition nnz into 512 row-buckets (8 rows each). Per block: LDS
//       histogram, ONE global atomicAdd per (block,bucket) to reserve space
//       (205*512 = 105K atomics, 16x fewer, all on 2 KB of hot lines), then
//       append (key, f32 val) records via LDS cursors. x f32->bf16 convert
//       rides along as extra blocks in the same grid.
//   P2: one block per bucket: accumulate segment into f32 LDS row-image
//       (block-local LDS atomics, duplicates exact), emit 8 bf16 rows
//       contiguous. Also obviates the 32 MB wb memset.
// ---------------------------------------------------------------------------
#define P1_CHUNK 8192
#define P1_BLOCKS ((NNZ_N + P1_CHUNK - 1) / P1_CHUNK)  // 205
#define NBUCK 512                                      // 8 rows per bucket
#define CAP 5120                                       // expect ~3276 +- 57
#define CVT_BLOCKS ((B_DIM * IN_F) / 8 / 256)          // 8192

__global__ __launch_bounds__(256) void p1_bucket_cvt(
    const float* __restrict__ vals, const int* __restrict__ rows,
    const int* __restrict__ cols, unsigned int* __restrict__ gcursor,
    unsigned long long* __restrict__ seg, const float* __restrict__ x,
    unsigned short* __restrict__ xb) {
  __shared__ unsigned int cnt[NBUCK];
  __shared__ unsigned int cur[NBUCK];
  const int b = blockIdx.x;
  if (b < P1_BLOCKS) {
    for (int i = threadIdx.x; i < NBUCK; i += 256) cnt[i] = 0;
    __syncthreads();
    const int base = b * P1_CHUNK;
#pragma unroll
    for (int j = 0; j < P1_CHUNK / 256; ++j) {
      int idx = base + j * 256 + threadIdx.x;
      if (idx < NNZ_N) atomicAdd(&cnt[rows[idx] >> 3], 1u);
    }
    __syncthreads();
    for (int i = threadIdx.x; i < NBUCK; i += 256)
      cur[i] = atomicAdd(&gcursor[i], cnt[i]);
    __syncthreads();
#pragma unroll
    for (int j = 0; j < P1_CHUNK / 256; ++j) {
      int idx = base + j * 256 + threadIdx.x;
      if (idx < NNZ_N) {
        int r = rows[idx];
        int c = cols[idx];
        float v = vals[idx];
        int bk = r >> 3;
        unsigned int pos = atomicAdd(&cur[bk], 1u);
        if (pos < CAP) {
          union {
            struct { unsigned int k; float v; } s;
            unsigned long long u;
          } e;
          e.s.k = (((unsigned int)(r & 7)) << 12) | (unsigned int)c;
          e.s.v = v;
          seg[(size_t)bk * CAP + pos] = e.u;
        }
      }
    }
  } else {
    size_t i = ((size_t)(b - P1_BLOCKS) * 256 + threadIdx.x) * 8;
    float4 a = *(const float4*)(x + i);
    float4 f = *(const float4*)(x + i + 4);
    ushort8 o;
    o[0] = f2bf(a.x); o[1] = f2bf(a.y); o[2] = f2bf(a.z); o[3] = f2bf(a.w);
    o[4] = f2bf(f.x); o[5] = f2bf(f.y); o[6] = f2bf(f.z); o[7] = f2bf(f.w);
    *(ushort8*)(xb + i) = o;
  }
}

__global__ __launch_bounds__(256) void p2_accum(
    const unsigned int* __restrict__ gcursor,
    const unsigned long long* __restrict__ seg,
    unsigned short* __restrict__ wb) {
  __shared__ float img[8 * 4096];  // 128 KB f32 row-image for 8 rows
  const int b = blockIdx.x;
  floatx4* img4 = (floatx4*)img;
  for (int i = threadIdx.x; i < 8192; i += 256) img4[i] = (floatx4)0.0f;
  __syncthreads();
  unsigned int n = gcursor[b];
  if (n > CAP) n = CAP;
  const unsigned long long* s = seg + (size_t)b * CAP;
  for (unsigned int i = threadIdx.x; i < n; i += 256) {
    unsigned long long e = s[i];
    unsigned int key = (unsigned int)e;
    union { unsigned int u; float f; } v;
    v.u = (unsigned int)(e >> 32);
    atomicAdd(&img[key & 0x7FFF], v.f);
  }
  __syncthreads();
  unsigned short* dst = wb + (size_t)b * 8 * 4096;
  for (int i = threadIdx.x; i < 4096; i += 256) {
    floatx4 a = img4[i * 2];
    floatx4 f = img4[i * 2 + 1];
    ushort8 o;
    o[0] = f2bf(a[0]); o[1] = f2bf(a[1]); o[2] = f2bf(a[2]); o[3] = f2bf(a[3]);
    o[4] = f2bf(f[0]); o[5] = f2bf(f[1]); o[6] = f2bf(f[2]); o[7] = f2bf(f[3]);
    *(ushort8*)(dst + i * 8) = o;
  }
}

// ---------------------------------------------------------------------------
// bf16 MFMA GEMM, C = A * B^T + bias  (unchanged from R2: m97-structure
// plateau, 128x128 tile, BK=64, XOR-swizzled LDS — conflicts measured 0)
// ---------------------------------------------------------------------------
__device__ inline void load_lds16(const unsigned short* g,
                                  const unsigned short* lds_base) {
  __builtin_amdgcn_global_load_lds(
      (const __attribute__((address_space(1))) unsigned int*)g,
      (__attribute__((address_space(3))) unsigned int*)lds_base, 16, 0, 0);
}

__global__ __launch_bounds__(256) void gemm_bt_bf16(
    const unsigned short* __restrict__ A, const unsigned short* __restrict__ Bt,
    const float* __restrict__ bias, float* __restrict__ C) {
  __shared__ unsigned short lA[128 * 64];  // [row][k] XOR-swizzled, unpadded
  __shared__ unsigned short lB[128 * 64];

  const int tid = threadIdx.x;
  const int wid = tid >> 6;
  const int lane = tid & 63;

  const int bm0 = blockIdx.y * 128;
  const int bn0 = blockIdx.x * 128;

  const int wm = (wid >> 1) * 64;
  const int wn = (wid & 1) * 64;

  floatx4 acc[4][4];
#pragma unroll
  for (int i = 0; i < 4; ++i)
#pragma unroll
    for (int j = 0; j < 4; ++j) acc[i][j] = (floatx4)0.0f;

  const int ldr = lane >> 3;
  const int ldc = ((lane & 7) ^ (ldr & 7)) * 8;

  const unsigned short* gA = A + (size_t)(bm0 + wid * 32) * IN_F;
  const unsigned short* gB = Bt + (size_t)(bn0 + wid * 32) * IN_F;

  for (int k0 = 0; k0 < IN_F; k0 += 64) {
#pragma unroll
    for (int j = 0; j < 4; ++j) {
      load_lds16(gA + (size_t)(j * 8 + ldr) * IN_F + k0 + ldc,
                 &lA[(wid * 32 + j * 8) * 64]);
      load_lds16(gB + (size_t)(j * 8 + ldr) * IN_F + k0 + ldc,
                 &lB[(wid * 32 + j * 8) * 64]);
    }
    __syncthreads();

    const int rr = lane & 15;
    const int rx = rr & 7;
    const int kq = lane >> 4;
#pragma unroll
    for (int ks = 0; ks < 2; ++ks) {
      const int kchunk = ks * 4 + kq;
      const int kcs = ((kchunk ^ rx) << 3);
      short8 af[4], bf[4];
#pragma unroll
      for (int i = 0; i < 4; ++i)
        af[i] = *(const short8*)&lA[(wm + i * 16 + rr) * 64 + kcs];
#pragma unroll
      for (int j = 0; j < 4; ++j)
        bf[j] = *(const short8*)&lB[(wn + j * 16 + rr) * 64 + kcs];
#pragma unroll
      for (int i = 0; i < 4; ++i)
#pragma unroll
        for (int j = 0; j < 4; ++j)
          acc[i][j] = __builtin_amdgcn_mfma_f32_16x16x32_bf16(
              af[i], bf[j], acc[i][j], 0, 0, 0);
    }
    __syncthreads();
  }

  const int cn = lane & 15;
  const int r0 = (lane >> 4) * 4;
#pragma unroll
  for (int j = 0; j < 4; ++j) {
    const int col = bn0 + wn + j * 16 + cn;
    const float bv = bias[col];
#pragma unroll
    for (int i = 0; i < 4; ++i) {
#pragma unroll
      for (int r = 0; r < 4; ++r) {
        const int row = bm0 + wm + i * 16 + r0 + r;
        C[(size_t)row * OUT_F + col] = acc[i][j][r] + bv;
      }
    }
  }
}

// ---------------------------------------------------------------------------
extern "C" void kernel_launch(void* const* d_in, const int* in_sizes, int n_in,
                              void* d_out, int out_size, void* d_ws,
                              size_t ws_size, hipStream_t stream) {
  const float* x = (const float*)d_in[0];
  const float* vals = (const float*)d_in[1];
  const int* rows = (const int*)d_in[2];
  const int* cols = (const int*)d_in[3];
  const float* bias = (const float*)d_in[4];
  float* out = (float*)d_out;

  // ws layout: gcursor 4KB @0 | seg 20MB @1MB | wb 32MB @32MB | xb 32MB @64MB
  unsigned int* gcursor = (unsigned int*)d_ws;
  unsigned long long* seg =
      (unsigned long long*)((char*)d_ws + ((size_t)1 << 20));
  unsigned short* wb = (unsigned short*)((char*)d_ws + ((size_t)32 << 20));
  unsigned short* xb = (unsigned short*)((char*)d_ws + ((size_t)64 << 20));

  (void)hipMemsetAsync(gcursor, 0, NBUCK * sizeof(unsigned int), stream);
  p1_bucket_cvt<<<P1_BLOCKS + CVT_BLOCKS, 256, 0, stream>>>(
      vals, rows, cols, gcursor, seg, x, xb);
  p2_accum<<<NBUCK, 256, 0, stream>>>(gcursor, seg, wb);

  dim3 grid(OUT_F / 128, B_DIM / 128);
  gemm_bt_bf16<<<grid, 256, 0, stream>>>(xb, wb, bias, out);
}